// Round 2
// baseline (201.932 us; speedup 1.0000x reference)
//
#include <hip/hip_runtime.h>
#include <hip/hip_bf16.h>

#define NB 2
#define NN 20000
#define NKN 16          // neighbors per node
#define NC 128          // C_IN
#define NM 9            // M kernels
#define NO 128          // C_OUT
#define NR (NB*NN)      // 40000 rows
#define KK (NM*NC)      // 1152 GEMM reduce dim
#define NPB 32          // nodes per fused block
#define YS 12           // padded y row stride (floats)
#define YB (NR/64)      // ycalc blocks = 625
#define SROW 2304       // S' row stride in bytes (1152 bf16)
#define WBOFF 73728u    // per-wave staging region base

typedef short bf16x8 __attribute__((ext_vector_type(8)));
typedef short bf16x4 __attribute__((ext_vector_type(4)));
typedef float f32x4  __attribute__((ext_vector_type(4)));
typedef unsigned short u16x8 __attribute__((ext_vector_type(8)));

union frg8 { bf16x4 h[2]; bf16x8 v; };

__device__ inline unsigned short bfb(float f) {
    union { __hip_bfloat16 b; unsigned short u; } t;
    t.b = __float2bfloat16(f);
    return t.u;
}

// ---------------- Kernel 1: prep (unchanged from R1) ----------------
// y = x·u^T. Wg repack: kk' = ct*144 + m*16 + ci; layout [kk'>>5][o128][kk'&31].
__global__ __launch_bounds__(256) void prep_kernel(const float* __restrict__ x,
                                                   const float* __restrict__ u,
                                                   const float* __restrict__ W,
                                                   float* __restrict__ y,
                                                   __hip_bfloat16* __restrict__ xb,
                                                   __hip_bfloat16* __restrict__ Wg,
                                                   int use_xb) {
    int tid = threadIdx.x;
    if (blockIdx.x < YB) {
        int wave = tid >> 6, lane = tid & 63;
        int lr = lane & 15, quad = lane >> 4;
        int node0 = blockIdx.x * 64 + wave * 16;
        long xbase = (long)(node0 + lr) * NC;

        bf16x8 afr[4];
        #pragma unroll
        for (int kc = 0; kc < 4; kc++) {
            const float* px = x + xbase + kc * 32 + quad * 8;
            float4 a0 = *(const float4*)px;
            float4 a1 = *(const float4*)(px + 4);
            union { bf16x8 v; unsigned short s[8]; __hip_bfloat16 h[8]; } af;
            af.h[0] = __float2bfloat16(a0.x); af.h[1] = __float2bfloat16(a0.y);
            af.h[2] = __float2bfloat16(a0.z); af.h[3] = __float2bfloat16(a0.w);
            af.h[4] = __float2bfloat16(a1.x); af.h[5] = __float2bfloat16(a1.y);
            af.h[6] = __float2bfloat16(a1.z); af.h[7] = __float2bfloat16(a1.w);
            afr[kc] = af.v;
            if (use_xb)
                *(u16x8*)((unsigned short*)xb + xbase + kc * 32 + quad * 8) =
                    *(u16x8*)&af.v;
        }
        int cs = (lr < NM) ? lr : 0;
        float fz = (lr < NM) ? 1.f : 0.f;
        f32x4 acc = (f32x4){0.f, 0.f, 0.f, 0.f};
        #pragma unroll
        for (int kc = 0; kc < 4; kc++) {
            const float* pu = u + cs * NC + kc * 32 + quad * 8;
            float4 b0 = *(const float4*)pu;
            float4 b1 = *(const float4*)(pu + 4);
            union { bf16x8 v; __hip_bfloat16 h[8]; } bf;
            bf.h[0] = __float2bfloat16(b0.x * fz); bf.h[1] = __float2bfloat16(b0.y * fz);
            bf.h[2] = __float2bfloat16(b0.z * fz); bf.h[3] = __float2bfloat16(b0.w * fz);
            bf.h[4] = __float2bfloat16(b1.x * fz); bf.h[5] = __float2bfloat16(b1.y * fz);
            bf.h[6] = __float2bfloat16(b1.z * fz); bf.h[7] = __float2bfloat16(b1.w * fz);
            acc = __builtin_amdgcn_mfma_f32_16x16x32_bf16(afr[kc], bf.v, acc, 0, 0, 0);
        }
        if (lr < NM) {
            #pragma unroll
            for (int r = 0; r < 4; r++)
                y[(long)(node0 + quad * 4 + r) * YS + lr] = acc[r];
        }
    } else {
        int t = (blockIdx.x - YB) * 256 + tid;   // t < 1152*128
        int kk = t >> 7;                         // kk' index
        int o = t & 127;
        int ctt = kk / 144;
        int rem = kk - ctt * 144;
        int m = rem >> 4;
        int ci = rem & 15;
        float v = W[m * 16384 + o * 128 + ctt * 16 + ci];
        Wg[((kk >> 5) * 128 + o) * 32 + (kk & 31)] = __float2bfloat16(v);
    }
}

// ---------------- Kernel 2: fused, MFMA phase A with streamed staging --------
// LDS = 81,920 B (2 blocks/CU, 16 waves/CU):
//   [0, 73728): S' 32 rows x 2304 B (kk' = ct*144+m*16+ci, XOR-swz (n&7)<<4)
//   [73728, 81920): 1 KiB per-wave ping-pong staging (q, then P slices)
// Phase A barrier-free (wave owns nodes 4wv..4wv+3). Operand-SWAPPED MFMA:
// acc = mfma(P_frag, q_frag) -> D[ci][m] -> one aligned ds_write_b64 per
// (node, ct) instead of 4 ds_write_b16. One __syncthreads before phase B.
template<bool BF16G>
__global__ __launch_bounds__(512, 4) void fused_kernel(const float* __restrict__ x,
                                                       const __hip_bfloat16* __restrict__ xb,
                                                       const int* __restrict__ adj,
                                                       const float* __restrict__ y,
                                                       const float* __restrict__ cv,
                                                       const __hip_bfloat16* __restrict__ Wg,
                                                       const float* __restrict__ bv,
                                                       float* __restrict__ out) {
    __shared__ __align__(16) char smem[81920];

    int tid = threadIdx.x;
    int node0 = blockIdx.x * NPB;
    int b = node0 / NN;
    int n0 = node0 - b * NN;
    int ln = tid >> 4, k = tid & 15;                 // node-in-block, edge
    int lane = tid & 63, wv = tid >> 6;
    int lr = lane & 15, quad = lane >> 4;

    // ---- A1: adj, y rows, own-edge gather (full 256B bf16 row -> 16 uint4) ----
    int a = adj[(n0 + ln) * NKN + k];
    long row = (long)(b * NN + ((a > 0) ? a - 1 : 0));

    const float* yn = y + (long)(node0 + ln) * YS;
    const float* ya = y + row * YS;
    float4 yn0 = *(const float4*)yn;
    float4 yn1 = *(const float4*)(yn + 4);
    float  yn8 = yn[8];
    float4 ya0 = *(const float4*)ya;
    float4 ya1 = *(const float4*)(ya + 4);
    float  ya8 = ya[8];

    uint4 pw[16];
    if (BF16G) {
        const uint4* xr = (const uint4*)(xb + row * NC);
        #pragma unroll
        for (int i = 0; i < 16; i++) pw[i] = xr[i];
    }

    // deg via ballot: node ln's 16 edge-threads are this wave's quad
    unsigned long long mk = __ballot(a > 0);
    int d = (int)__popcll((mk >> (quad * 16)) & 0xFFFFull);
    float di = (d > 0) ? 1.f / (float)d : 0.f;

    // ---- A2: softmax; q' = softmax * deg_inv, dual-bf16 (hi/lo) split ----
    float sel = (a > 0) ? 1.f : 0.f;
    float l[NM];
    l[0] = yn0.x - sel * ya0.x + cv[0];
    l[1] = yn0.y - sel * ya0.y + cv[1];
    l[2] = yn0.z - sel * ya0.z + cv[2];
    l[3] = yn0.w - sel * ya0.w + cv[3];
    l[4] = yn1.x - sel * ya1.x + cv[4];
    l[5] = yn1.y - sel * ya1.y + cv[5];
    l[6] = yn1.z - sel * ya1.z + cv[6];
    l[7] = yn1.w - sel * ya1.w + cv[7];
    l[8] = yn8   - sel * ya8   + cv[8];
    float mx = l[0];
    #pragma unroll
    for (int m = 1; m < NM; m++) mx = fmaxf(mx, l[m]);
    float e_[NM]; float sum = 0.f;
    #pragma unroll
    for (int m = 0; m < NM; m++) { e_[m] = expf(l[m] - mx); sum += e_[m]; }
    float qf = ((a > 0) ? (1.f / sum) : 0.f) * di;

    union { u16x8 v[2]; unsigned short s[16]; } H, L;
    #pragma unroll
    for (int m = 0; m < NM; m++) {
        float qv = e_[m] * qf;
        unsigned short hb = bfb(qv);
        union { unsigned short u; __hip_bfloat16 bb; } hh; hh.u = hb;
        float hf = __bfloat162float(hh.bb);
        H.s[m] = hb;
        L.s[m] = bfb(qv - hf);
    }
    #pragma unroll
    for (int m = NM; m < 16; m++) { H.s[m] = 0; L.s[m] = 0; }

    char* wb = smem + WBOFF + wv * 1024;
    unsigned wba = (unsigned)(unsigned long long)(uintptr_t)wb;

    // ---- A3: q staging per owned node g -> A-side frags in registers ----
    frg8 afrag[4];
    #pragma unroll
    for (int g = 0; g < 4; ++g) {
        if (quad == g) {
            unsigned qo = (unsigned)((k >> 2) * 128 + (k & 3) * 32);
            *(u16x8*)(wb + qo)        = H.v[0];
            *(u16x8*)(wb + qo + 16)   = H.v[1];
            *(u16x8*)(wb + qo + 512)  = L.v[0];
            *(u16x8*)(wb + qo + 528)  = L.v[1];
        }
        asm volatile("s_waitcnt lgkmcnt(0)" ::: "memory");
        __builtin_amdgcn_sched_barrier(0);
        bf16x4 qa0, qa1;
        unsigned qaddr = wba + (unsigned)(quad * 256 + lr * 8);
        asm volatile("ds_read_b64_tr_b16 %0, %2 offset:0\n\t"
                     "ds_read_b64_tr_b16 %1, %2 offset:128"
                     : "=&v"(qa0), "=&v"(qa1) : "v"(qaddr));
        asm volatile("s_waitcnt lgkmcnt(0)" ::: "memory");
        __builtin_amdgcn_sched_barrier(0);
        afrag[g].h[0] = qa0; afrag[g].h[1] = qa1;
    }

    // P slice writer: iteration it = ct*4 + g; 512B slice into half (it&1)
    #define WRITE_P(IT) {                                                        \
        int ct_ = (IT) >> 2, g_ = (IT) & 3;                                      \
        if (quad == g_) {                                                        \
            char* o = wb + (((IT) & 1) * 512 + (lr >> 2) * 128 + (lr & 3) * 32); \
            if (BF16G) {                                                         \
                *(uint4*)o        = pw[2 * ct_];                                 \
                *(uint4*)(o + 16) = pw[2 * ct_ + 1];                             \
            } else {                                                             \
                const float4* xf = (const float4*)(x + row * NC);                \
                _Pragma("unroll")                                                \
                for (int hh = 0; hh < 2; hh++) {                                 \
                    float4 f0 = xf[ct_ * 4 + hh * 2];                            \
                    float4 f1 = xf[ct_ * 4 + hh * 2 + 1];                        \
                    union { u16x8 v; unsigned short s[8]; } ov;                  \
                    ov.s[0] = bfb(f0.x); ov.s[1] = bfb(f0.y);                    \
                    ov.s[2] = bfb(f0.z); ov.s[3] = bfb(f0.w);                    \
                    ov.s[4] = bfb(f1.x); ov.s[5] = bfb(f1.y);                    \
                    ov.s[6] = bfb(f1.z); ov.s[7] = bfb(f1.w);                    \
                    *(u16x8*)(o + hh * 16) = ov.v;                               \
                }                                                                \
            }                                                                    \
        }                                                                        \
    }

    // ---- A4: streamed (node, ct) slices; swapped-operand MFMA; b64 S' ----
    WRITE_P(0)
    asm volatile("s_waitcnt lgkmcnt(0)" ::: "memory");
    __builtin_amdgcn_sched_barrier(0);

    #pragma unroll
    for (int it = 0; it < 32; ++it) {
        int ct = it >> 2, g = it & 3;
        int n = (wv << 2) + g;

        bf16x4 p0, p1;
        unsigned paddr = wba + (unsigned)((it & 1) * 512 + (quad & 1) * 256 + lr * 8);
        asm volatile("ds_read_b64_tr_b16 %0, %2 offset:0\n\t"
                     "ds_read_b64_tr_b16 %1, %2 offset:128"
                     : "=&v"(p0), "=&v"(p1) : "v"(paddr));
        if (it < 31) WRITE_P(it + 1)                 // other half: no WAR hazard
        asm volatile("s_waitcnt lgkmcnt(0)" ::: "memory");
        __builtin_amdgcn_sched_barrier(0);

        frg8 pf; pf.h[0] = p0; pf.h[1] = p1;
        f32x4 acc = (f32x4){0.f, 0.f, 0.f, 0.f};
        acc = __builtin_amdgcn_mfma_f32_16x16x32_bf16(pf.v, afrag[g].v, acc, 0, 0, 0);

        bf16x4 sv;
        sv[0] = (short)bfb(acc[0]);
        sv[1] = (short)bfb(acc[1]);
        sv[2] = (short)bfb(acc[2]);
        sv[3] = (short)bfb(acc[3]);
        unsigned off = ((unsigned)(ct * 288 + lr * 32 + quad * 8)) ^
                       ((unsigned)((n & 7) << 4));
        if (lr < 9)
            *(bf16x4*)(smem + n * SROW + off) = sv;  // aligned ds_write_b64
    }
    #undef WRITE_P

    __syncthreads();                                 // S' ready block-wide

    // ---- phase B: 32x1152 @ 1152x128 (verified structure, stride 2304) ----
    const short* wg = reinterpret_cast<const short*>(Wg);
    f32x4 acc0 = (f32x4){0.f, 0.f, 0.f, 0.f};
    f32x4 acc1 = (f32x4){0.f, 0.f, 0.f, 0.f};
    unsigned swzB = (unsigned)((lr & 7) << 4);       // (16+lr)&7 == lr&7
    #pragma unroll 9
    for (int kc = 0; kc < 36; kc++) {
        bf16x8 bfrag = *(const bf16x8*)(wg + ((kc * 128) + wv * 16 + lr) * 32 + quad * 8);
        unsigned ao = ((unsigned)(kc * 64 + quad * 16)) ^ swzB;
        bf16x8 a0 = *(const bf16x8*)(smem + (unsigned)(lr * SROW) + ao);
        bf16x8 a1 = *(const bf16x8*)(smem + (unsigned)((16 + lr) * SROW) + ao);
        acc0 = __builtin_amdgcn_mfma_f32_16x16x32_bf16(a0, bfrag, acc0, 0, 0, 0);
        acc1 = __builtin_amdgcn_mfma_f32_16x16x32_bf16(a1, bfrag, acc1, 0, 0, 0);
    }

    int col = wv * 16 + lr;
    float bb = bv[col];
    int rbase = node0 + quad * 4;
    #pragma unroll
    for (int r = 0; r < 4; r++) {
        out[(long)(rbase + r) * NO + col]      = acc0[r] + bb;
        out[(long)(rbase + 16 + r) * NO + col] = acc1[r] + bb;
    }
}

extern "C" void kernel_launch(void* const* d_in, const int* in_sizes, int n_in,
                              void* d_out, int out_size, void* d_ws, size_t ws_size,
                              hipStream_t stream) {
    const float* x   = (const float*)d_in[0];   // (B,N,C)
    const int*   adj = (const int*)  d_in[1];   // (N,K)
    const float* W   = (const float*)d_in[2];   // (M,O,C)
    const float* bv  = (const float*)d_in[3];   // (O,)
    const float* u   = (const float*)d_in[4];   // (M,C)
    const float* cv  = (const float*)d_in[5];   // (M,)
    float* out = (float*)d_out;

    char* ws = (char*)d_ws;
    float* y = (float*)ws;                                     // 1,920,000 B
    __hip_bfloat16* Wg = (__hip_bfloat16*)(ws + 1920000);      //   294,912 B
    __hip_bfloat16* xb = (__hip_bfloat16*)(ws + 2214912);      // 10,240,000 B
    bool use_xb = (ws_size >= (size_t)12454912);

    prep_kernel<<<YB + 576, 256, 0, stream>>>(x, u, W, y, use_xb ? xb : nullptr, Wg,
                                              use_xb ? 1 : 0);
    if (use_xb)
        fused_kernel<true><<<NR / NPB, 512, 0, stream>>>(x, xb, adj, y, cv, Wg, bv, out);
    else
        fused_kernel<false><<<NR / NPB, 512, 0, stream>>>(x, xb, adj, y, cv, Wg, bv, out);
}

// Round 3
// 139.428 us; speedup vs baseline: 1.4483x; 1.4483x over previous
//
#include <hip/hip_runtime.h>
#include <hip/hip_bf16.h>

#define NB 2
#define NN 20000
#define NKN 16          // neighbors per node
#define NC 128          // C_IN
#define NM 9            // M kernels
#define NO 128          // C_OUT
#define NR (NB*NN)      // 40000 rows
#define KK 1152         // NM*NC GEMM reduce dim
#define NPB 32          // nodes per fused block
#define YS 12           // padded y row stride (floats)
#define YB (NR/64)      // ycalc blocks = 625
#define SROW 2304       // S' row stride bytes
#define PBASE 73728u    // staging region base in smem
#define SMEMB 139264    // 73728 + 16 waves * 4096

typedef short bf16x8 __attribute__((ext_vector_type(8)));
typedef short bf16x4 __attribute__((ext_vector_type(4)));
typedef float f32x4  __attribute__((ext_vector_type(4)));
typedef unsigned short u16x8 __attribute__((ext_vector_type(8)));

typedef __attribute__((address_space(1))) const void gas_void;
typedef __attribute__((address_space(3))) void las_void;

union frg8 { bf16x4 h[2]; bf16x8 v; };

__device__ inline unsigned short bfb(float f) {
    union { __hip_bfloat16 b; unsigned short u; } t;
    t.b = __float2bfloat16(f);
    return t.u;
}

// ---------------- Kernel 1: prep (unchanged; ct-order Wg) ----------------
// y = x·u^T. Wg repack: kk' = ct*144 + m*16 + ci; layout [kk'>>5][o128][kk'&31].
__global__ __launch_bounds__(256) void prep_kernel(const float* __restrict__ x,
                                                   const float* __restrict__ u,
                                                   const float* __restrict__ W,
                                                   float* __restrict__ y,
                                                   __hip_bfloat16* __restrict__ xb,
                                                   __hip_bfloat16* __restrict__ Wg,
                                                   int use_xb) {
    int tid = threadIdx.x;
    if (blockIdx.x < YB) {
        int wave = tid >> 6, lane = tid & 63;
        int lr = lane & 15, quad = lane >> 4;
        int node0 = blockIdx.x * 64 + wave * 16;
        long xbase = (long)(node0 + lr) * NC;

        bf16x8 afr[4];
        #pragma unroll
        for (int kc = 0; kc < 4; kc++) {
            const float* px = x + xbase + kc * 32 + quad * 8;
            float4 a0 = *(const float4*)px;
            float4 a1 = *(const float4*)(px + 4);
            union { bf16x8 v; unsigned short s[8]; __hip_bfloat16 h[8]; } af;
            af.h[0] = __float2bfloat16(a0.x); af.h[1] = __float2bfloat16(a0.y);
            af.h[2] = __float2bfloat16(a0.z); af.h[3] = __float2bfloat16(a0.w);
            af.h[4] = __float2bfloat16(a1.x); af.h[5] = __float2bfloat16(a1.y);
            af.h[6] = __float2bfloat16(a1.z); af.h[7] = __float2bfloat16(a1.w);
            afr[kc] = af.v;
            if (use_xb)
                *(u16x8*)((unsigned short*)xb + xbase + kc * 32 + quad * 8) =
                    *(u16x8*)&af.v;
        }
        int cs = (lr < NM) ? lr : 0;
        float fz = (lr < NM) ? 1.f : 0.f;
        f32x4 acc = (f32x4){0.f, 0.f, 0.f, 0.f};
        #pragma unroll
        for (int kc = 0; kc < 4; kc++) {
            const float* pu = u + cs * NC + kc * 32 + quad * 8;
            float4 b0 = *(const float4*)pu;
            float4 b1 = *(const float4*)(pu + 4);
            union { bf16x8 v; __hip_bfloat16 h[8]; } bf;
            bf.h[0] = __float2bfloat16(b0.x * fz); bf.h[1] = __float2bfloat16(b0.y * fz);
            bf.h[2] = __float2bfloat16(b0.z * fz); bf.h[3] = __float2bfloat16(b0.w * fz);
            bf.h[4] = __float2bfloat16(b1.x * fz); bf.h[5] = __float2bfloat16(b1.y * fz);
            bf.h[6] = __float2bfloat16(b1.z * fz); bf.h[7] = __float2bfloat16(b1.w * fz);
            acc = __builtin_amdgcn_mfma_f32_16x16x32_bf16(afr[kc], bf.v, acc, 0, 0, 0);
        }
        if (lr < NM) {
            #pragma unroll
            for (int r = 0; r < 4; r++)
                y[(long)(node0 + quad * 4 + r) * YS + lr] = acc[r];
        }
    } else {
        int t = (blockIdx.x - YB) * 256 + tid;   // t < 1152*128
        int kk = t >> 7;
        int o = t & 127;
        int ctt = kk / 144;
        int rem = kk - ctt * 144;
        int m = rem >> 4;
        int ci = rem & 15;
        float v = W[m * 16384 + o * 128 + ctt * 16 + ci];
        Wg[((kk >> 5) * 128 + o) * 32 + (kk & 31)] = __float2bfloat16(v);
    }
}

// ---------------- Kernel 2: fused (1024 thr, gl_lds pipeline) ----------------
// LDS 139,264 B: S' [0,73728) (32 x 2304, kk'=ct*144+m*16+ci, XOR-swz (n&7)<<4);
// staging [73728, +16*4096): per-wave 4-slot x 1KB ring (q overlays slots 0-1,
// consumed before first gl_lds lands). 16 waves x 2 nodes each, barrier-free
// phase A: softmax (lanes<32) -> q dual-bf16 stage -> tr_read q frags ->
// counted-vmcnt gl_lds pipeline over 8 (node, ct-pair) slots, swapped-operand
// MFMA -> b64 S' writes. One __syncthreads; phase B on waves 0-7 (verified).
template<bool BF16G>
__global__ __launch_bounds__(1024, 4) void fused_kernel(const float* __restrict__ x,
                                                        const __hip_bfloat16* __restrict__ xb,
                                                        const int* __restrict__ adj,
                                                        const float* __restrict__ y,
                                                        const float* __restrict__ cv,
                                                        const __hip_bfloat16* __restrict__ Wg,
                                                        const float* __restrict__ bv,
                                                        float* __restrict__ out) {
    __shared__ __align__(16) char smem[SMEMB];

    int tid = threadIdx.x;
    int lane = tid & 63, wv = tid >> 6;              // 16 waves
    int lr = lane & 15, quad = lane >> 4;
    int node0 = blockIdx.x * NPB;
    int b = node0 / NN;
    int n0 = node0 - b * NN;

    // ---- A1: softmax lanes (lane<32): lanes[0,16)=node 2wv, [16,32)=2wv+1 ----
    bool sm = (lane < 32);
    int lnode = wv * 2 + (quad & 1);                 // valid when sm
    int a = 0;
    if (sm) a = adj[(n0 + lnode) * NKN + lr];
    int rowint = b * NN + ((a > 0) ? a - 1 : 0);

    float4 yn0 = {0,0,0,0}, yn1 = {0,0,0,0}, ya0 = {0,0,0,0}, ya1 = {0,0,0,0};
    float yn8 = 0.f, ya8 = 0.f;
    if (sm) {
        const float* yn = y + (long)(node0 + lnode) * YS;
        const float* ya = y + (long)rowint * YS;
        yn0 = *(const float4*)yn;  yn1 = *(const float4*)(yn + 4);  yn8 = yn[8];
        ya0 = *(const float4*)ya;  ya1 = *(const float4*)(ya + 4);  ya8 = ya[8];
    }

    unsigned long long mk = __ballot(a > 0);
    int d = (int)__popcll((mk >> (quad * 16)) & 0xFFFFull);
    float di = (d > 0) ? 1.f / (float)d : 0.f;

    // ---- gather lane mapping: slot byte pos*16 = kq*128 + j*32 + h*16 ----
    int pos = lane & 31;
    int e   = ((pos >> 3) << 2) | ((pos >> 1) & 3); // edge this lane fetches
    int hh  = pos & 1;                              // 16B half within 32B ct chunk
    int ctl = lane >> 5;                            // ct-local within 1KB pair-slot
    int rowA = __shfl(rowint, e);                   // node 2wv, edge e row
    int rowB = __shfl(rowint, 16 + e);              // node 2wv+1

    unsigned wboff = PBASE + (unsigned)(wv * 4096);
    unsigned sb = (unsigned)(uintptr_t)&smem[0];
    unsigned wba = sb + wboff;

    // ---- A2: softmax; q' = softmax * deg_inv, dual-bf16 hi/lo ----
    if (sm) {
        float sel = (a > 0) ? 1.f : 0.f;
        float l[NM];
        l[0] = yn0.x - sel * ya0.x + cv[0];
        l[1] = yn0.y - sel * ya0.y + cv[1];
        l[2] = yn0.z - sel * ya0.z + cv[2];
        l[3] = yn0.w - sel * ya0.w + cv[3];
        l[4] = yn1.x - sel * ya1.x + cv[4];
        l[5] = yn1.y - sel * ya1.y + cv[5];
        l[6] = yn1.z - sel * ya1.z + cv[6];
        l[7] = yn1.w - sel * ya1.w + cv[7];
        l[8] = yn8   - sel * ya8   + cv[8];
        float mx = l[0];
        #pragma unroll
        for (int m = 1; m < NM; m++) mx = fmaxf(mx, l[m]);
        float e_[NM]; float sum = 0.f;
        #pragma unroll
        for (int m = 0; m < NM; m++) { e_[m] = expf(l[m] - mx); sum += e_[m]; }
        float qf = ((a > 0) ? (1.f / sum) : 0.f) * di;

        union { u16x8 v[2]; unsigned short s[16]; } H, L;
        #pragma unroll
        for (int m = 0; m < NM; m++) {
            float qv = e_[m] * qf;
            unsigned short hb = bfb(qv);
            union { unsigned short u; __hip_bfloat16 bb; } hv; hv.u = hb;
            H.s[m] = hb;
            L.s[m] = bfb(qv - __bfloat162float(hv.bb));
        }
        #pragma unroll
        for (int m = NM; m < 16; m++) { H.s[m] = 0; L.s[m] = 0; }

        // node nn=(quad&1) q tile at wboff + nn*1024 (overlays P slots 0-1)
        unsigned qo = wboff + (unsigned)((quad & 1) * 1024 +
                                         (lr >> 2) * 128 + (lr & 3) * 32);
        *(u16x8*)(smem + qo)       = H.v[0];
        *(u16x8*)(smem + qo + 16)  = H.v[1];
        *(u16x8*)(smem + qo + 512) = L.v[0];
        *(u16x8*)(smem + qo + 528) = L.v[1];
    }
    asm volatile("s_waitcnt lgkmcnt(0)" ::: "memory");
    __builtin_amdgcn_sched_barrier(0);

    // ---- q frags (B-operand of swapped MFMA), verified R2 addressing ----
    bf16x4 qa0, qa1, qb0, qb1;
    unsigned qra = wba + (unsigned)(quad * 256 + lr * 8);
    asm volatile("ds_read_b64_tr_b16 %0, %2 offset:0\n\t"
                 "ds_read_b64_tr_b16 %1, %2 offset:128"
                 : "=&v"(qa0), "=&v"(qa1) : "v"(qra));
    asm volatile("ds_read_b64_tr_b16 %0, %2 offset:1024\n\t"
                 "ds_read_b64_tr_b16 %1, %2 offset:1152"
                 : "=&v"(qb0), "=&v"(qb1) : "v"(qra));
    asm volatile("s_waitcnt lgkmcnt(0)" ::: "memory");
    __builtin_amdgcn_sched_barrier(0);
    frg8 fragA, fragB;
    fragA.h[0] = qa0; fragA.h[1] = qa1;
    fragB.h[0] = qb0; fragB.h[1] = qb1;

    // slot S (0..7): node nn=S>>2, ct-pair t=S&3; ring buffer slot S&3 (1KB)
    #define ISSUE(S) {                                                          \
        long rr = (long)(((S) >> 2) ? rowB : rowA);                             \
        const __hip_bfloat16* gp = xb + rr * NC +                               \
                                   (2 * ((S) & 3) + ctl) * 16 + hh * 8;         \
        __builtin_amdgcn_global_load_lds((gas_void*)gp,                         \
            (las_void*)(smem + wboff + (unsigned)(((S) & 3) * 1024)), 16, 0, 0);\
    }

    #define PITER(S, NW) {                                                      \
        if (BF16G) {                                                            \
            asm volatile("s_waitcnt vmcnt(" #NW ")" ::: "memory");              \
            __builtin_amdgcn_sched_barrier(0);                                  \
        } else {                                                                \
            long rr_ = (long)(((S) >> 2) ? rowB : rowA);                        \
            const float* fp = x + rr_ * NC + (2 * ((S) & 3) + ctl) * 16 + hh * 8;\
            float4 f0 = *(const float4*)fp;                                     \
            float4 f1 = *(const float4*)(fp + 4);                               \
            union { u16x8 v; unsigned short s[8]; } ov;                         \
            ov.s[0] = bfb(f0.x); ov.s[1] = bfb(f0.y); ov.s[2] = bfb(f0.z);      \
            ov.s[3] = bfb(f0.w); ov.s[4] = bfb(f1.x); ov.s[5] = bfb(f1.y);      \
            ov.s[6] = bfb(f1.z); ov.s[7] = bfb(f1.w);                           \
            *(u16x8*)(smem + wboff + (unsigned)(((S) & 3) * 1024 + lane * 16))  \
                = ov.v;                                                         \
            asm volatile("s_waitcnt lgkmcnt(0)" ::: "memory");                  \
            __builtin_amdgcn_sched_barrier(0);                                  \
        }                                                                       \
        bf16x4 p0a, p0b, p1a, p1b;                                              \
        unsigned pr_ = wba + (unsigned)(((S) & 3) * 1024 +                      \
                                        (quad & 1) * 256 + lr * 8);             \
        asm volatile("ds_read_b64_tr_b16 %0, %4 offset:0\n\t"                   \
                     "ds_read_b64_tr_b16 %1, %4 offset:128\n\t"                 \
                     "ds_read_b64_tr_b16 %2, %4 offset:512\n\t"                 \
                     "ds_read_b64_tr_b16 %3, %4 offset:640"                     \
                     : "=&v"(p0a), "=&v"(p0b), "=&v"(p1a), "=&v"(p1b)           \
                     : "v"(pr_));                                               \
        asm volatile("s_waitcnt lgkmcnt(0)" ::: "memory");                      \
        __builtin_amdgcn_sched_barrier(0);                                      \
        if (BF16G && (S) < 4) { ISSUE((S) + 4) }                                \
        {                                                                       \
            int nl_ = 2 * wv + ((S) >> 2);                                      \
            unsigned swz_ = (unsigned)((nl_ & 7) << 4);                         \
            f32x4 z = (f32x4){0.f, 0.f, 0.f, 0.f};                              \
            frg8 pf; pf.h[0] = p0a; pf.h[1] = p0b;                              \
            f32x4 ac = __builtin_amdgcn_mfma_f32_16x16x32_bf16(pf.v,            \
                           ((S) >> 2) ? fragB.v : fragA.v, z, 0, 0, 0);         \
            bf16x4 sv;                                                          \
            sv[0] = (short)bfb(ac[0]); sv[1] = (short)bfb(ac[1]);               \
            sv[2] = (short)bfb(ac[2]); sv[3] = (short)bfb(ac[3]);               \
            unsigned so = ((unsigned)((2 * ((S) & 3)) * 288 + lr * 32 +         \
                                      quad * 8)) ^ swz_;                        \
            if (lr < 9) *(bf16x4*)(smem + nl_ * SROW + so) = sv;                \
            pf.h[0] = p1a; pf.h[1] = p1b;                                       \
            ac = __builtin_amdgcn_mfma_f32_16x16x32_bf16(pf.v,                  \
                     ((S) >> 2) ? fragB.v : fragA.v, z, 0, 0, 0);               \
            sv[0] = (short)bfb(ac[0]); sv[1] = (short)bfb(ac[1]);               \
            sv[2] = (short)bfb(ac[2]); sv[3] = (short)bfb(ac[3]);               \
            so = ((unsigned)((2 * ((S) & 3) + 1) * 288 + lr * 32 +              \
                             quad * 8)) ^ swz_;                                 \
            if (lr < 9) *(bf16x4*)(smem + nl_ * SROW + so) = sv;                \
        }                                                                       \
    }

    if (BF16G) {
        asm volatile("s_waitcnt vmcnt(0)" ::: "memory");   // clean vmcnt baseline
        __builtin_amdgcn_sched_barrier(0);
        ISSUE(0) ISSUE(1) ISSUE(2) ISSUE(3)
    }
    PITER(0, 3) PITER(1, 3) PITER(2, 3) PITER(3, 3)
    PITER(4, 3) PITER(5, 2) PITER(6, 1) PITER(7, 0)
    #undef PITER
    #undef ISSUE

    __syncthreads();                                   // S' ready block-wide
    __builtin_amdgcn_sched_barrier(0);

    // ---- phase B: waves 0-7, verified 32x1152 @ 1152x128 loop ----
    if (wv < 8) {
        const short* wg = reinterpret_cast<const short*>(Wg);
        f32x4 acc0 = (f32x4){0.f, 0.f, 0.f, 0.f};
        f32x4 acc1 = (f32x4){0.f, 0.f, 0.f, 0.f};
        unsigned swzB = (unsigned)((lr & 7) << 4);     // (16+lr)&7 == lr&7
        #pragma unroll 9
        for (int kc = 0; kc < 36; kc++) {
            bf16x8 bfrag = *(const bf16x8*)(wg + ((kc * 128) + wv * 16 + lr) * 32
                                            + quad * 8);
            unsigned ao = ((unsigned)(kc * 64 + quad * 16)) ^ swzB;
            bf16x8 a0 = *(const bf16x8*)(smem + (unsigned)(lr * SROW) + ao);
            bf16x8 a1 = *(const bf16x8*)(smem + (unsigned)((16 + lr) * SROW) + ao);
            acc0 = __builtin_amdgcn_mfma_f32_16x16x32_bf16(a0, bfrag, acc0, 0, 0, 0);
            acc1 = __builtin_amdgcn_mfma_f32_16x16x32_bf16(a1, bfrag, acc1, 0, 0, 0);
        }

        int col = wv * 16 + lr;
        float bb = bv[col];
        int rbase = node0 + quad * 4;
        #pragma unroll
        for (int r = 0; r < 4; r++) {
            out[(long)(rbase + r) * NO + col]      = acc0[r] + bb;
            out[(long)(rbase + 16 + r) * NO + col] = acc1[r] + bb;
        }
    }
}

extern "C" void kernel_launch(void* const* d_in, const int* in_sizes, int n_in,
                              void* d_out, int out_size, void* d_ws, size_t ws_size,
                              hipStream_t stream) {
    const float* x   = (const float*)d_in[0];   // (B,N,C)
    const int*   adj = (const int*)  d_in[1];   // (N,K)
    const float* W   = (const float*)d_in[2];   // (M,O,C)
    const float* bv  = (const float*)d_in[3];   // (O,)
    const float* u   = (const float*)d_in[4];   // (M,C)
    const float* cv  = (const float*)d_in[5];   // (M,)
    float* out = (float*)d_out;

    char* ws = (char*)d_ws;
    float* y = (float*)ws;                                     // 1,920,000 B
    __hip_bfloat16* Wg = (__hip_bfloat16*)(ws + 1920000);      //   294,912 B
    __hip_bfloat16* xb = (__hip_bfloat16*)(ws + 2214912);      // 10,240,000 B
    bool use_xb = (ws_size >= (size_t)12454912);

    prep_kernel<<<YB + 576, 256, 0, stream>>>(x, u, W, y, use_xb ? xb : nullptr, Wg,
                                              use_xb ? 1 : 0);
    if (use_xb)
        fused_kernel<true><<<NR / NPB, 1024, 0, stream>>>(x, xb, adj, y, cv, Wg, bv, out);
    else
        fused_kernel<false><<<NR / NPB, 1024, 0, stream>>>(x, xb, adj, y, cv, Wg, bv, out);
}